// Round 2
// baseline (700.119 us; speedup 1.0000x reference)
//
#include <hip/hip_runtime.h>

// Problem constants (from reference)
constexpr int Hdim = 1024;
constexpr int Wdim = 1024;
constexpr int HWp  = Hdim * Wdim;     // 1,048,576 pixels
constexpr int Kp   = 24;              // composite layers
constexpr int KSp  = 50;              // shadow layers
constexpr int Cp   = 14;              // feature channels
constexpr int Np   = 500000;          // points

// ---- Pre-pass: pack features (N x 14 f32) + 1/r^2 into 64 B rows ----------
__global__ __launch_bounds__(256) void repack_k(
    const float2* __restrict__ feat2,   // N*7 float2 (14 f32/row, 56 B)
    const float*  __restrict__ rad,     // N f32
    float4* __restrict__ ws)            // N*4 float4 (64 B rows)
{
    int i = blockIdx.x * 256 + threadIdx.x;
    if (i >= Np) return;
    const float2* s = feat2 + (long long)i * 7;
    float f[14];
#pragma unroll
    for (int j = 0; j < 7; ++j) { float2 v = s[j]; f[2 * j] = v.x; f[2 * j + 1] = v.y; }
    float r   = rad[i];
    float inv = 1.0f / (r * r);
    float4* d = ws + (long long)i * 4;
    d[0] = make_float4(f[0],  f[1],  f[2],  f[3]);
    d[1] = make_float4(f[4],  f[5],  f[6],  f[7]);
    d[2] = make_float4(f[8],  f[9],  f[10], f[11]);
    d[3] = make_float4(f[12], f[13], inv,   0.0f);
}

// ---- Image kernel: per-pixel K-layer alpha composite, H-flipped output ----
template <bool PACKED>
__global__ __launch_bounds__(256) void image_k(
    const int*    __restrict__ idx,     // (K, H, W) int32
    const float*  __restrict__ d2s,     // (K, H, W) f32
    const float4* __restrict__ packed,  // N*4 float4 (PACKED path)
    const float2* __restrict__ feat2,   // N*7 float2 (fallback path)
    const float*  __restrict__ rad,     // N f32      (fallback path)
    float* __restrict__ out)            // (H, W, C) f32
{
    const int p = blockIdx.x * 256 + threadIdx.x;

    float acc[Cp];
#pragma unroll
    for (int c = 0; c < Cp; ++c) acc[c] = 0.0f;
    float T = 1.0f;

    for (int k = 0; k < Kp; ++k) {
        int   i  = idx[k * HWp + p];
        float d2 = d2s[k * HWp + p];
        // T < 1e-5: remaining contribution bounded by 1e-5 << 2e-2 threshold
        bool live = (i >= 0) && (T >= 1e-5f);
        if (live) {
            float f[Cp];
            float inv;
            if (PACKED) {
                const float4* row = packed + (long long)i * 4;
                float4 a = row[0], b = row[1], c4 = row[2], d4 = row[3];
                f[0] = a.x;  f[1] = a.y;  f[2]  = a.z;  f[3]  = a.w;
                f[4] = b.x;  f[5] = b.y;  f[6]  = b.z;  f[7]  = b.w;
                f[8] = c4.x; f[9] = c4.y; f[10] = c4.z; f[11] = c4.w;
                f[12] = d4.x; f[13] = d4.y; inv = d4.z;
            } else {
                const float2* s = feat2 + (long long)i * 7;
#pragma unroll
                for (int j = 0; j < 7; ++j) { float2 v = s[j]; f[2 * j] = v.x; f[2 * j + 1] = v.y; }
                float r = rad[i];
                inv = 1.0f / (r * r);
            }
            float alpha = 1.0f - d2 * inv;
            float wgt   = alpha * T;
            T *= (1.0f - alpha);
#pragma unroll
            for (int c = 0; c < Cp; ++c) acc[c] += wgt * f[c];
        }
        if (!__any(T >= 1e-5f)) break;  // whole wave dead -> stop streaming
    }

    // Stage 256 px x 14 f32 (14336 B) in LDS, then coalesced uint4 stores.
    __shared__ __align__(16) float lds[256 * Cp];
    float* my = &lds[threadIdx.x * Cp];
#pragma unroll
    for (int j = 0; j < Cp; ++j) my[j] = acc[j];
    __syncthreads();

    const int base_pix = blockIdx.x * 256;           // all 256 px share h (W=1024)
    const int x0 = base_pix & (Wdim - 1);
    const int hb = base_pix >> 10;
    float* dst = out + ((long long)(Hdim - 1 - hb) * Wdim + x0) * Cp;  // H-flip
    uint4* dst4 = (uint4*)dst;                        // 3584 floats/block -> 16B aligned
    const uint4* src4 = (const uint4*)lds;
#pragma unroll
    for (int j = threadIdx.x; j < 256 * Cp / 4; j += 256) dst4[j] = src4[j];
}

// ---- Shadow visibility: sorted zbuf -> early exit; benign-race 1.0 stores --
__global__ __launch_bounds__(256) void shadow_k(
    const int4*   __restrict__ sidx4,  // (KS, HW/4) int4
    const float4* __restrict__ zb4,    // (KS, HW/4) float4
    float* __restrict__ vis)           // N f32 (pre-zeroed)
{
    const int Q = HWp / 4;
    const int t = blockIdx.x * 256 + threadIdx.x;  // < Q
    float4 z0 = zb4[t];                            // k = 0 plane

    for (int k = 0; k < KSp; ++k) {
        float4 z = zb4[k * Q + t];
        bool b0 = (z.x - z0.x) < 0.1f;
        bool b1 = (z.y - z0.y) < 0.1f;
        bool b2 = (z.z - z0.z) < 0.1f;
        bool b3 = (z.w - z0.w) < 0.1f;
        bool any = b0 | b1 | b2 | b3;
        if (any) {
            int4 si = sidx4[k * Q + t];
            if (b0 && si.x >= 0) vis[si.x] = 1.0f;
            if (b1 && si.y >= 0) vis[si.y] = 1.0f;
            if (b2 && si.z >= 0) vis[si.z] = 1.0f;
            if (b3 && si.w >= 0) vis[si.w] = 1.0f;
        }
        if (!__any(any)) break;  // zbuf sorted along k: condition is monotone
    }
}

extern "C" void kernel_launch(void* const* d_in, const int* in_sizes, int n_in,
                              void* d_out, int out_size, void* d_ws, size_t ws_size,
                              hipStream_t stream)
{
    const int*   idx  = (const int*)d_in[0];
    const float* d2s  = (const float*)d_in[1];
    const int*   sidx = (const int*)d_in[2];
    const float* zbuf = (const float*)d_in[3];
    const float* rad  = (const float*)d_in[4];
    const float* feat = (const float*)d_in[5];

    float* out_img = (float*)d_out;
    float* out_vis = out_img + (long long)HWp * Cp;

    // visible starts at 0 (d_out is re-poisoned 0xAA before every launch)
    hipMemsetAsync(out_vis, 0, Np * sizeof(float), stream);

    const bool use_packed = ws_size >= (size_t)Np * 64;
    if (use_packed) {
        repack_k<<<(Np + 255) / 256, 256, 0, stream>>>(
            (const float2*)feat, rad, (float4*)d_ws);
        image_k<true><<<HWp / 256, 256, 0, stream>>>(
            idx, d2s, (const float4*)d_ws, nullptr, nullptr, out_img);
    } else {
        image_k<false><<<HWp / 256, 256, 0, stream>>>(
            idx, d2s, nullptr, (const float2*)feat, rad, out_img);
    }

    shadow_k<<<HWp / 4 / 256, 256, 0, stream>>>(
        (const int4*)sidx, (const float4*)zbuf, (float*)out_vis);
}